// Round 3
// baseline (617.490 us; speedup 1.0000x reference)
//
#include <hip/hip_runtime.h>
#include <math.h>

typedef _Float16 v8h __attribute__((ext_vector_type(8)));
typedef float v4f __attribute__((ext_vector_type(4)));
typedef float v16f __attribute__((ext_vector_type(16)));

// ---------------------------------------------------------------- convert
// NCHW f32 [4,256,56,200] -> NHWC f16 [4,56,200,256]
__global__ void __launch_bounds__(256) convert_kernel(const float* __restrict__ in,
                                                      _Float16* __restrict__ out) {
  const int cb = blockIdx.x * 64, h = blockIdx.y, n = blockIdx.z;
  __shared__ _Float16 tile[64][202];
  const int tid = threadIdx.x;
#pragma unroll 1
  for (int it = 0; it < 50; ++it) {
    int idx = it * 256 + tid;
    int c = idx / 200, w = idx - c * 200;
    tile[c][w] = (_Float16)in[(((size_t)n * 256 + cb + c) * 56 + h) * 200 + w];
  }
  __syncthreads();
#pragma unroll 1
  for (int it = 0; it < 50; ++it) {
    int idx = it * 256 + tid;
    int w = idx >> 6, c = idx & 63;
    out[(((size_t)n * 56 + h) * 200 + w) * 256 + cb + c] = tile[c][w];
  }
}

// ---------------------------------------------------------------- merged weight repack
// rc: OIHW f32 [128,256,3,3] -> [tap][32][128][8] f16
// bb: 6x OIHW f32 [128,128,3,3] -> slots [tap][16][128][8] f16 (slot 2i=w1[i], 2i+1=w2[i])
// dp: f32 [112,128] -> f16 flat
__global__ void __launch_bounds__(256) repack_all_kernel(
    const float* __restrict__ rc_w, const float* __restrict__ bb_w1,
    const float* __restrict__ bb_w2, const float* __restrict__ dp_w,
    _Float16* __restrict__ wrc, _Float16* __restrict__ wbb,
    _Float16* __restrict__ wdp) {
  const int RC = 128 * 256 * 9;
  const int BB = 128 * 128 * 9;
  int i = blockIdx.x * 256 + threadIdx.x;
  if (i < RC) {
    int tap = i % 9, r = i / 9;
    int ci = r % 256, co = r / 256;
    wrc[(((size_t)tap * 32 + (ci >> 3)) * 128 + co) * 8 + (ci & 7)] = (_Float16)rc_w[i];
  } else if (i < RC + 6 * BB) {
    int j = i - RC;
    int blk = j / BB, k = j - blk * BB;
    int tap = k % 9, r = k / 9;
    int ci = r % 128, co = r / 128;
    const float* src = (blk < 3) ? (bb_w1 + (size_t)blk * BB) : (bb_w2 + (size_t)(blk - 3) * BB);
    int slot = (blk < 3) ? (2 * blk) : (2 * (blk - 3) + 1);
    wbb[(size_t)slot * BB + (((size_t)tap * 16 + (ci >> 3)) * 128 + co) * 8 + (ci & 7)] =
        (_Float16)src[k];
  } else if (i < RC + 6 * BB + 112 * 128) {
    int j = i - RC - 6 * BB;
    wdp[j] = (_Float16)dp_w[j];
  }
}

// ---------------------------------------------------------------- tiny MLP + SE
__global__ void __launch_bounds__(128) mlp_kernel(
    const float* __restrict__ sps, const float* __restrict__ fc1_w,
    const float* __restrict__ fc1_b, const float* __restrict__ fc2_w,
    const float* __restrict__ fc2_b, const float* __restrict__ se_rw,
    const float* __restrict__ se_rb, const float* __restrict__ se_ew,
    const float* __restrict__ se_eb, float* __restrict__ sig) {
  __shared__ float buf[128];
  const int j = threadIdx.x;
  for (int b = 0; b < 4; ++b) {
    float h1 = fmaxf(sps[b] * fc1_w[j] + fc1_b[j], 0.f);
    __syncthreads();
    buf[j] = h1;
    __syncthreads();
    float hm = fc2_b[j];
    for (int k = 0; k < 128; ++k) hm += buf[k] * fc2_w[j * 128 + k];
    __syncthreads();
    buf[j] = hm;
    __syncthreads();
    float t = se_rb[j];
    for (int k = 0; k < 128; ++k) t += buf[k] * se_rw[j * 128 + k];
    t = fmaxf(t, 0.f);
    __syncthreads();
    buf[j] = t;
    __syncthreads();
    float se = se_eb[j];
    for (int k = 0; k < 128; ++k) se += buf[k] * se_ew[j * 128 + k];
    sig[b * 128 + j] = 1.f / (1.f + expf(-se));
  }
}

// ---------------------------------------------------------------- 3x3 conv, implicit GEMM, 32x32x16 f16 MFMA
// act: NHWC f16 [4,56,200,CIN]; wr: [9][CIN/8][128][8] f16; out: NHWC f16 [4,56,200,128]
// Block: 8h x 16w x 64cout (cout split across blocks for occupancy; grid 13x7x8).
// Wave: 2h x 16w (M=32) x 64cout (2 N-tiles of 32) -> 2 MFMAs per A ds_read_b128
// (LDS pipe 12cy vs matrix 16cy per iteration -> MFMA-favored).
// LDS halo tile [10][18][4 ch-groups of 8], XOR-swizzled ch-group for bank balance.
// MODE 0: out = relu((conv + bias)*s + t) * sig_se          (rc conv)
// MODE 1: out = relu(conv*s + t)                            (bb conv1)
// MODE 2: out = relu(xprev + conv*s + t)                    (bb conv2 + residual)
template <int CIN, int MODE>
__global__ void __launch_bounds__(256) conv3x3_kernel(
    const _Float16* __restrict__ act, const _Float16* __restrict__ wr,
    const _Float16* __restrict__ xprev, const float* __restrict__ bias,
    const float* __restrict__ sc, const float* __restrict__ tr,
    const float* __restrict__ sig_se, _Float16* __restrict__ out) {
  const int wt = blockIdx.x, ht = blockIdx.y;
  const int n = blockIdx.z >> 1, cg = blockIdx.z & 1;
  const int h0 = ht * 8, w0 = wt * 16;
  const int tid = threadIdx.x;
  const int wave = tid >> 6, lane = tid & 63;
  const int l31 = lane & 31, khalf = lane >> 5;
  const int rowin = l31 >> 4, col = l31 & 15;

  __shared__ alignas(16) _Float16 lds[10 * 18 * 32];

  v16f acc[2];
#pragma unroll
  for (int i = 0; i < 2; ++i)
#pragma unroll
    for (int r = 0; r < 16; ++r) acc[i][r] = 0.f;

#pragma unroll 1
  for (int c0 = 0; c0 < CIN; c0 += 32) {
    __syncthreads();
    // stage halo tile [10][18][32ch], zero-padded, swizzled ch-groups
#pragma unroll
    for (int it = 0; it < 3; ++it) {
      int chunk = it * 256 + tid;
      if (chunk < 720) {
        int pos = chunk >> 2, part = chunk & 3;
        int hh = pos / 18, wq = pos - hh * 18;
        int gh = h0 - 1 + hh, gw = w0 - 1 + wq;
        v8h v = {(_Float16)0, (_Float16)0, (_Float16)0, (_Float16)0,
                 (_Float16)0, (_Float16)0, (_Float16)0, (_Float16)0};
        if ((unsigned)gh < 56u && (unsigned)gw < 200u)
          v = *(const v8h*)(act + (((size_t)n * 56 + gh) * 200 + gw) * CIN + c0 + part * 8);
        int swz = part ^ (pos & 3) ^ ((pos >> 2) & 3);
        *(v8h*)(lds + pos * 32 + swz * 8) = v;
      }
    }
    __syncthreads();
#pragma unroll
    for (int kk = 0; kk < 32; kk += 16) {
#pragma unroll
      for (int dy = 0; dy < 3; ++dy) {
#pragma unroll
        for (int dx = 0; dx < 3; ++dx) {
          const int tap = dy * 3 + dx;
          const int p = (wave * 2 + rowin + dy) * 18 + col + dx;
          const int g = (kk >> 3) + khalf;
          const int swz = g ^ (p & 3) ^ ((p >> 2) & 3);
          v8h a = *(const v8h*)(lds + p * 32 + swz * 8);
          const _Float16* wp =
              wr + (((size_t)tap * (CIN / 8) + ((c0 + kk) >> 3) + khalf) * 128 + cg * 64 + l31) * 8;
#pragma unroll
          for (int nt = 0; nt < 2; ++nt) {
            v8h b = *(const v8h*)(wp + nt * 32 * 8);
            acc[nt] = __builtin_amdgcn_mfma_f32_32x32x16_f16(a, b, acc[nt], 0, 0, 0);
          }
        }
      }
    }
  }

  // epilogue: 32x32 D layout: col(N=cout)=lane&31, row(M)=(r&3)+8*(r>>2)+4*khalf
#pragma unroll
  for (int nt = 0; nt < 2; ++nt) {
    const int c = cg * 64 + nt * 32 + l31;
    const float s = sc[c], t = tr[c];
    float bb = 0.f, sg = 1.f;
    if constexpr (MODE == 0) {
      bb = bias[c];
      sg = sig_se[n * 128 + c];
    }
#pragma unroll
    for (int r = 0; r < 16; ++r) {
      const int rowidx = (r & 3) + 8 * (r >> 2) + 4 * khalf;
      const int h = h0 + wave * 2 + (rowidx >> 4);
      const int w = w0 + (rowidx & 15);
      if (w < 200) {
        float v = acc[nt][r];
        size_t oidx = (((size_t)n * 56 + h) * 200 + w) * 128 + c;
        if constexpr (MODE == 0) v = fmaxf((v + bb) * s + t, 0.f) * sg;
        if constexpr (MODE == 1) v = fmaxf(v * s + t, 0.f);
        if constexpr (MODE == 2) v = fmaxf((float)xprev[oidx] + v * s + t, 0.f);
        out[oidx] = (_Float16)v;
      }
    }
  }
}

// ---------------------------------------------------------------- depth proj (MFMA) + fused softmax
// x: [44800][128] f16; wdp: [112][128] f16; dp_b: [112] f32
// depth out: f16 [pos][112] (z-contiguous for gridsample)
__global__ void __launch_bounds__(256) depth_proj_softmax_kernel(
    const _Float16* __restrict__ x, const _Float16* __restrict__ wdp,
    const float* __restrict__ dp_b, _Float16* __restrict__ depth) {
  const int wave = threadIdx.x >> 6, lane = threadIdx.x & 63;
  const int q = lane >> 4, l16 = lane & 15;
  const int pos0 = blockIdx.x * 64 + wave * 16;

  v4f acc[7];
#pragma unroll
  for (int nt = 0; nt < 7; ++nt) {
    float bv = dp_b[nt * 16 + l16];
    acc[nt] = {bv, bv, bv, bv};
  }
#pragma unroll
  for (int c0 = 0; c0 < 128; c0 += 32) {
    v8h a = *(const v8h*)(x + (size_t)(pos0 + l16) * 128 + c0 + q * 8);
#pragma unroll
    for (int nt = 0; nt < 7; ++nt) {
      v8h b = *(const v8h*)(wdp + (size_t)(nt * 16 + l16) * 128 + c0 + q * 8);
      acc[nt] = __builtin_amdgcn_mfma_f32_16x16x32_f16(a, b, acc[nt], 0, 0, 0);
    }
  }
  // D layout: col=l16 -> dch (within 16), row=q*4+r -> position
  float m[4];
#pragma unroll
  for (int r = 0; r < 4; ++r) {
    m[r] = acc[0][r];
#pragma unroll
    for (int nt = 1; nt < 7; ++nt) m[r] = fmaxf(m[r], acc[nt][r]);
  }
#pragma unroll
  for (int off = 1; off < 16; off <<= 1)
#pragma unroll
    for (int r = 0; r < 4; ++r) m[r] = fmaxf(m[r], __shfl_xor(m[r], off));
  float s[4] = {0.f, 0.f, 0.f, 0.f};
#pragma unroll
  for (int nt = 0; nt < 7; ++nt)
#pragma unroll
    for (int r = 0; r < 4; ++r) {
      float e = expf(acc[nt][r] - m[r]);
      acc[nt][r] = e;
      s[r] += e;
    }
#pragma unroll
  for (int off = 1; off < 16; off <<= 1)
#pragma unroll
    for (int r = 0; r < 4; ++r) s[r] += __shfl_xor(s[r], off);
#pragma unroll
  for (int r = 0; r < 4; ++r) {
    const float inv = 1.f / s[r];
    const size_t p = pos0 + q * 4 + r;
#pragma unroll
    for (int nt = 0; nt < 7; ++nt)
      depth[p * 112 + nt * 16 + l16] = (_Float16)(acc[nt][r] * inv);
  }
}

// ---------------------------------------------------------------- trilinear grid sample (C=1)
// grids: [1,4,128,128,16,3] f32; depth: f16 [n*11200 + y*200 + x][112 z]; out: [4,128,128,16] f32
__global__ void __launch_bounds__(256) gridsample_kernel(
    const float* __restrict__ grids, const _Float16* __restrict__ depth,
    float* __restrict__ out) {
  const int i = blockIdx.x * 256 + threadIdx.x;
  const int n = i >> 18;  // 128*128*16 = 2^18 per batch
  const float gx = grids[(size_t)i * 3];
  const float gy = grids[(size_t)i * 3 + 1];
  const float gz = grids[(size_t)i * 3 + 2];
  const float ix = (gx + 1.f) * 100.f - 0.5f;  // W=200
  const float iy = (gy + 1.f) * 28.f - 0.5f;   // H=56
  const float iz = (gz + 1.f) * 56.f - 0.5f;   // D=112
  const float xf = floorf(ix), yf = floorf(iy), zf = floorf(iz);
  const int x0 = (int)xf, y0 = (int)yf, z0 = (int)zf;
  const float fx = ix - xf, fy = iy - yf, fz = iz - zf;
  const bool zv0 = (unsigned)z0 < 112u;
  const bool zv1 = (unsigned)(z0 + 1) < 112u;
  const float wz0 = 1.f - fz, wz1 = fz;
  float acc = 0.f;
#pragma unroll
  for (int dy = 0; dy < 2; ++dy) {
    const int yi = y0 + dy;
    const float wy = dy ? fy : 1.f - fy;
#pragma unroll
    for (int dx = 0; dx < 2; ++dx) {
      const int xi = x0 + dx;
      const float wx = dx ? fx : 1.f - fx;
      if ((unsigned)xi < 200u && (unsigned)yi < 56u) {
        const _Float16* bp = depth + ((size_t)n * 11200 + yi * 200 + xi) * 112;
        float v0 = zv0 ? (float)bp[z0] : 0.f;
        float v1 = zv1 ? (float)bp[z0 + 1] : 0.f;
        acc += (wx * wy) * (wz0 * v0 + wz1 * v1);
      }
    }
  }
  out[i] = acc;
}

// ---------------------------------------------------------------- launch
extern "C" void kernel_launch(void* const* d_in, const int* in_sizes, int n_in,
                              void* d_out, int out_size, void* d_ws, size_t ws_size,
                              hipStream_t stream) {
  (void)in_sizes; (void)n_in; (void)out_size; (void)ws_size;
  const float* img = (const float*)d_in[0];
  const float* sps = (const float*)d_in[1];
  const float* grids = (const float*)d_in[2];
  const float* rc_w = (const float*)d_in[3];
  const float* rc_b = (const float*)d_in[4];
  const float* rc_s = (const float*)d_in[5];
  const float* rc_t = (const float*)d_in[6];
  const float* fc1_w = (const float*)d_in[7];
  const float* fc1_b = (const float*)d_in[8];
  const float* fc2_w = (const float*)d_in[9];
  const float* fc2_b = (const float*)d_in[10];
  const float* se_rw = (const float*)d_in[11];
  const float* se_rb = (const float*)d_in[12];
  const float* se_ew = (const float*)d_in[13];
  const float* se_eb = (const float*)d_in[14];
  const float* bb_w1 = (const float*)d_in[15];
  const float* bb_s1 = (const float*)d_in[16];
  const float* bb_t1 = (const float*)d_in[17];
  const float* bb_w2 = (const float*)d_in[18];
  const float* bb_s2 = (const float*)d_in[19];
  const float* bb_t2 = (const float*)d_in[20];
  const float* dp_w = (const float*)d_in[21];
  const float* dp_b = (const float*)d_in[22];
  float* outp = (float*)d_out;

  char* ws = (char*)d_ws;
  _Float16* act16 = (_Float16*)(ws + 0);   // 22,937,600 B
  _Float16* depth16 = (_Float16*)(ws + 0); // reuses act16 slot (act16 dead post rc-conv)
  _Float16* xa = (_Float16*)(ws + 23068672);
  _Float16* xb = (_Float16*)(ws + 23068672 + 11534336);
  _Float16* yb = (_Float16*)(ws + 23068672 + 2 * 11534336);
  _Float16* wrc = (_Float16*)(ws + 57671680);              // 589,824 B
  _Float16* wdp = (_Float16*)(ws + 57671680 + 589824);     // 28,672 B
  _Float16* wbb = (_Float16*)(ws + 58327040);              // 1,769,472 B
  float* sig = (float*)(ws + 58327040 + 1769472);          // 2,048 B

  repack_all_kernel<<<dim3(4664), 256, 0, stream>>>(rc_w, bb_w1, bb_w2, dp_w, wrc, wbb, wdp);
  mlp_kernel<<<1, 128, 0, stream>>>(sps, fc1_w, fc1_b, fc2_w, fc2_b, se_rw, se_rb,
                                    se_ew, se_eb, sig);
  convert_kernel<<<dim3(4, 56, 4), 256, 0, stream>>>(img, act16);

  dim3 cgrid(13, 7, 8);  // 728 blocks: cout split (z = n*2 + cg)
  conv3x3_kernel<256, 0><<<cgrid, 256, 0, stream>>>(act16, wrc, nullptr, rc_b, rc_s,
                                                    rc_t, sig, xa);
  _Float16* xcur = xa;
  _Float16* xnxt = xb;
  for (int i = 0; i < 3; ++i) {
    conv3x3_kernel<128, 1><<<cgrid, 256, 0, stream>>>(
        xcur, wbb + (size_t)(2 * i) * 147456, nullptr, nullptr, bb_s1 + i * 128,
        bb_t1 + i * 128, nullptr, yb);
    conv3x3_kernel<128, 2><<<cgrid, 256, 0, stream>>>(
        yb, wbb + (size_t)(2 * i + 1) * 147456, xcur, nullptr, bb_s2 + i * 128,
        bb_t2 + i * 128, nullptr, xnxt);
    _Float16* t = xcur;
    xcur = xnxt;
    xnxt = t;
  }

  depth_proj_softmax_kernel<<<dim3(700), 256, 0, stream>>>(xcur, wdp, dp_b, depth16);
  gridsample_kernel<<<dim3(4096), 256, 0, stream>>>(grids, depth16, outp);
}

// Round 4
// 492.390 us; speedup vs baseline: 1.2541x; 1.2541x over previous
//
#include <hip/hip_runtime.h>
#include <math.h>

typedef _Float16 v8h __attribute__((ext_vector_type(8)));
typedef float v4f __attribute__((ext_vector_type(4)));
typedef float v16f __attribute__((ext_vector_type(16)));

// ---------------------------------------------------------------- convert
// NCHW f32 [4,256,56,200] -> NHWC f16 [4,56,200,256]
__global__ void __launch_bounds__(256) convert_kernel(const float* __restrict__ in,
                                                      _Float16* __restrict__ out) {
  const int cb = blockIdx.x * 64, h = blockIdx.y, n = blockIdx.z;
  __shared__ _Float16 tile[64][202];
  const int tid = threadIdx.x;
#pragma unroll 1
  for (int it = 0; it < 50; ++it) {
    int idx = it * 256 + tid;
    int c = idx / 200, w = idx - c * 200;
    tile[c][w] = (_Float16)in[(((size_t)n * 256 + cb + c) * 56 + h) * 200 + w];
  }
  __syncthreads();
#pragma unroll 1
  for (int it = 0; it < 50; ++it) {
    int idx = it * 256 + tid;
    int w = idx >> 6, c = idx & 63;
    out[(((size_t)n * 56 + h) * 200 + w) * 256 + cb + c] = tile[c][w];
  }
}

// ---------------------------------------------------------------- merged weight repack
__global__ void __launch_bounds__(256) repack_all_kernel(
    const float* __restrict__ rc_w, const float* __restrict__ bb_w1,
    const float* __restrict__ bb_w2, const float* __restrict__ dp_w,
    _Float16* __restrict__ wrc, _Float16* __restrict__ wbb,
    _Float16* __restrict__ wdp) {
  const int RC = 128 * 256 * 9;
  const int BB = 128 * 128 * 9;
  int i = blockIdx.x * 256 + threadIdx.x;
  if (i < RC) {
    int tap = i % 9, r = i / 9;
    int ci = r % 256, co = r / 256;
    wrc[(((size_t)tap * 32 + (ci >> 3)) * 128 + co) * 8 + (ci & 7)] = (_Float16)rc_w[i];
  } else if (i < RC + 6 * BB) {
    int j = i - RC;
    int blk = j / BB, k = j - blk * BB;
    int tap = k % 9, r = k / 9;
    int ci = r % 128, co = r / 128;
    const float* src = (blk < 3) ? (bb_w1 + (size_t)blk * BB) : (bb_w2 + (size_t)(blk - 3) * BB);
    int slot = (blk < 3) ? (2 * blk) : (2 * (blk - 3) + 1);
    wbb[(size_t)slot * BB + (((size_t)tap * 16 + (ci >> 3)) * 128 + co) * 8 + (ci & 7)] =
        (_Float16)src[k];
  } else if (i < RC + 6 * BB + 112 * 128) {
    int j = i - RC - 6 * BB;
    wdp[j] = (_Float16)dp_w[j];
  }
}

// ---------------------------------------------------------------- tiny MLP + SE
__global__ void __launch_bounds__(128) mlp_kernel(
    const float* __restrict__ sps, const float* __restrict__ fc1_w,
    const float* __restrict__ fc1_b, const float* __restrict__ fc2_w,
    const float* __restrict__ fc2_b, const float* __restrict__ se_rw,
    const float* __restrict__ se_rb, const float* __restrict__ se_ew,
    const float* __restrict__ se_eb, float* __restrict__ sig) {
  __shared__ float buf[128];
  const int j = threadIdx.x;
  for (int b = 0; b < 4; ++b) {
    float h1 = fmaxf(sps[b] * fc1_w[j] + fc1_b[j], 0.f);
    __syncthreads();
    buf[j] = h1;
    __syncthreads();
    float hm = fc2_b[j];
    for (int k = 0; k < 128; ++k) hm += buf[k] * fc2_w[j * 128 + k];
    __syncthreads();
    buf[j] = hm;
    __syncthreads();
    float t = se_rb[j];
    for (int k = 0; k < 128; ++k) t += buf[k] * se_rw[j * 128 + k];
    t = fmaxf(t, 0.f);
    __syncthreads();
    buf[j] = t;
    __syncthreads();
    float se = se_eb[j];
    for (int k = 0; k < 128; ++k) se += buf[k] * se_ew[j * 128 + k];
    sig[b * 128 + j] = 1.f / (1.f + expf(-se));
  }
}

// ---------------------------------------------------------------- 3x3 conv, implicit GEMM, 32x32x16 f16 MFMA
// Round-2 tiling (block 8h x 16w x 128cout, wave M32 x N128, 4 MFMA per ds_read)
// + double-buffered LDS with register prefetch: one barrier per K-chunk; chunk
// k+1's global loads issue after the barrier and are consumed at the next LDS
// write, hiding global latency behind ~600cy of MFMA. A single wave/SIMD can
// then keep the MFMA pipe busy despite the grid-bound ~12% occupancy.
// MODE 0: out = relu((conv + bias)*s + t) * sig_se          (rc conv)
// MODE 1: out = relu(conv*s + t)                            (bb conv1)
// MODE 2: out = relu(xprev + conv*s + t)                    (bb conv2 + residual)
template <int CIN, int MODE>
__global__ void __launch_bounds__(256) conv3x3_kernel(
    const _Float16* __restrict__ act, const _Float16* __restrict__ wr,
    const _Float16* __restrict__ xprev, const float* __restrict__ bias,
    const float* __restrict__ sc, const float* __restrict__ tr,
    const float* __restrict__ sig_se, _Float16* __restrict__ out) {
  const int wt = blockIdx.x, ht = blockIdx.y, n = blockIdx.z;
  const int h0 = ht * 8, w0 = wt * 16;
  const int tid = threadIdx.x;
  const int wave = tid >> 6, lane = tid & 63;
  const int l31 = lane & 31, khalf = lane >> 5;
  const int rowin = l31 >> 4, col = l31 & 15;

  __shared__ alignas(16) _Float16 lds[2][10 * 18 * 32];

  // per-thread staging constants (720 v8h slots over 3 rounds of 256 threads)
  size_t goff[3];
  int loff[3];
  bool exist[3], ok[3];
#pragma unroll
  for (int it = 0; it < 3; ++it) {
    int chunk = it * 256 + tid;
    int pos = chunk >> 2, part = chunk & 3;
    int hh = pos / 18, wq = pos - hh * 18;
    int gh = h0 - 1 + hh, gw = w0 - 1 + wq;
    exist[it] = chunk < 720;
    bool inimg = (unsigned)gh < 56u && (unsigned)gw < 200u;
    ok[it] = exist[it] && inimg;
    int swz = part ^ (pos & 3) ^ ((pos >> 2) & 3);
    loff[it] = pos * 32 + swz * 8;
    int ghc = ok[it] ? gh : 0, gwc = ok[it] ? gw : 0;
    goff[it] = (((size_t)n * 56 + ghc) * 200 + gwc) * CIN + part * 8;
  }

  const v8h zero8 = {(_Float16)0, (_Float16)0, (_Float16)0, (_Float16)0,
                     (_Float16)0, (_Float16)0, (_Float16)0, (_Float16)0};
  v8h pre[3];
#pragma unroll
  for (int it = 0; it < 3; ++it) pre[it] = ok[it] ? *(const v8h*)(act + goff[it]) : zero8;

  v16f acc[4];
#pragma unroll
  for (int i = 0; i < 4; ++i)
#pragma unroll
    for (int r = 0; r < 16; ++r) acc[i][r] = 0.f;

#pragma unroll 1
  for (int c0 = 0; c0 < CIN; c0 += 32) {
    _Float16* ldsb = &lds[(c0 >> 5) & 1][0];
    // commit prefetched chunk to this buffer
#pragma unroll
    for (int it = 0; it < 3; ++it)
      if (exist[it]) *(v8h*)(ldsb + loff[it]) = pre[it];
    __syncthreads();
    // prefetch next chunk (latency hidden behind the MFMA block below)
    if (c0 + 32 < CIN) {
#pragma unroll
      for (int it = 0; it < 3; ++it)
        pre[it] = ok[it] ? *(const v8h*)(act + goff[it] + c0 + 32) : zero8;
    }
#pragma unroll
    for (int kk = 0; kk < 32; kk += 16) {
#pragma unroll
      for (int dy = 0; dy < 3; ++dy) {
#pragma unroll
        for (int dx = 0; dx < 3; ++dx) {
          const int tap = dy * 3 + dx;
          const int p = (wave * 2 + rowin + dy) * 18 + col + dx;
          const int g = (kk >> 3) + khalf;
          const int swz = g ^ (p & 3) ^ ((p >> 2) & 3);
          v8h a = *(const v8h*)(ldsb + p * 32 + swz * 8);
          const _Float16* wp =
              wr + (((size_t)tap * (CIN / 8) + ((c0 + kk) >> 3) + khalf) * 128 + l31) * 8;
#pragma unroll
          for (int nt = 0; nt < 4; ++nt) {
            v8h b = *(const v8h*)(wp + nt * 32 * 8);
            acc[nt] = __builtin_amdgcn_mfma_f32_32x32x16_f16(a, b, acc[nt], 0, 0, 0);
          }
        }
      }
    }
  }

  // epilogue: 32x32 D layout: col(N=cout)=lane&31, row(M)=(r&3)+8*(r>>2)+4*khalf
#pragma unroll
  for (int nt = 0; nt < 4; ++nt) {
    const int c = nt * 32 + l31;
    const float s = sc[c], t = tr[c];
    float bb = 0.f, sg = 1.f;
    if constexpr (MODE == 0) {
      bb = bias[c];
      sg = sig_se[n * 128 + c];
    }
#pragma unroll
    for (int r = 0; r < 16; ++r) {
      const int rowidx = (r & 3) + 8 * (r >> 2) + 4 * khalf;
      const int h = h0 + wave * 2 + (rowidx >> 4);
      const int w = w0 + (rowidx & 15);
      if (w < 200) {
        float v = acc[nt][r];
        size_t oidx = (((size_t)n * 56 + h) * 200 + w) * 128 + c;
        if constexpr (MODE == 0) v = fmaxf((v + bb) * s + t, 0.f) * sg;
        if constexpr (MODE == 1) v = fmaxf(v * s + t, 0.f);
        if constexpr (MODE == 2) v = fmaxf((float)xprev[oidx] + v * s + t, 0.f);
        out[oidx] = (_Float16)v;
      }
    }
  }
}

// ---------------------------------------------------------------- depth proj (MFMA) + fused softmax
// x: [44800][128] f16; wdp: [112][128] f16; dp_b: [112] f32
// depth out: f16 [pos][112] (z-contiguous for gridsample)
__global__ void __launch_bounds__(256) depth_proj_softmax_kernel(
    const _Float16* __restrict__ x, const _Float16* __restrict__ wdp,
    const float* __restrict__ dp_b, _Float16* __restrict__ depth) {
  const int wave = threadIdx.x >> 6, lane = threadIdx.x & 63;
  const int q = lane >> 4, l16 = lane & 15;
  const int pos0 = blockIdx.x * 64 + wave * 16;

  v4f acc[7];
#pragma unroll
  for (int nt = 0; nt < 7; ++nt) {
    float bv = dp_b[nt * 16 + l16];
    acc[nt] = {bv, bv, bv, bv};
  }
#pragma unroll
  for (int c0 = 0; c0 < 128; c0 += 32) {
    v8h a = *(const v8h*)(x + (size_t)(pos0 + l16) * 128 + c0 + q * 8);
#pragma unroll
    for (int nt = 0; nt < 7; ++nt) {
      v8h b = *(const v8h*)(wdp + (size_t)(nt * 16 + l16) * 128 + c0 + q * 8);
      acc[nt] = __builtin_amdgcn_mfma_f32_16x16x32_f16(a, b, acc[nt], 0, 0, 0);
    }
  }
  // D layout: col=l16 -> dch (within 16), row=q*4+r -> position
  float m[4];
#pragma unroll
  for (int r = 0; r < 4; ++r) {
    m[r] = acc[0][r];
#pragma unroll
    for (int nt = 1; nt < 7; ++nt) m[r] = fmaxf(m[r], acc[nt][r]);
  }
#pragma unroll
  for (int off = 1; off < 16; off <<= 1)
#pragma unroll
    for (int r = 0; r < 4; ++r) m[r] = fmaxf(m[r], __shfl_xor(m[r], off));
  float s[4] = {0.f, 0.f, 0.f, 0.f};
#pragma unroll
  for (int nt = 0; nt < 7; ++nt)
#pragma unroll
    for (int r = 0; r < 4; ++r) {
      float e = expf(acc[nt][r] - m[r]);
      acc[nt][r] = e;
      s[r] += e;
    }
#pragma unroll
  for (int off = 1; off < 16; off <<= 1)
#pragma unroll
    for (int r = 0; r < 4; ++r) s[r] += __shfl_xor(s[r], off);
#pragma unroll
  for (int r = 0; r < 4; ++r) {
    const float inv = 1.f / s[r];
    const size_t p = pos0 + q * 4 + r;
#pragma unroll
    for (int nt = 0; nt < 7; ++nt)
      depth[p * 112 + nt * 16 + l16] = (_Float16)(acc[nt][r] * inv);
  }
}

// ---------------------------------------------------------------- trilinear grid sample (C=1)
// grids: [1,4,128,128,16,3] f32; depth: f16 [n*11200 + y*200 + x][112 z]; out: [4,128,128,16] f32
__global__ void __launch_bounds__(256) gridsample_kernel(
    const float* __restrict__ grids, const _Float16* __restrict__ depth,
    float* __restrict__ out) {
  const int i = blockIdx.x * 256 + threadIdx.x;
  const int n = i >> 18;  // 128*128*16 = 2^18 per batch
  const float gx = grids[(size_t)i * 3];
  const float gy = grids[(size_t)i * 3 + 1];
  const float gz = grids[(size_t)i * 3 + 2];
  const float ix = (gx + 1.f) * 100.f - 0.5f;  // W=200
  const float iy = (gy + 1.f) * 28.f - 0.5f;   // H=56
  const float iz = (gz + 1.f) * 56.f - 0.5f;   // D=112
  const float xf = floorf(ix), yf = floorf(iy), zf = floorf(iz);
  const int x0 = (int)xf, y0 = (int)yf, z0 = (int)zf;
  const float fx = ix - xf, fy = iy - yf, fz = iz - zf;
  const bool zv0 = (unsigned)z0 < 112u;
  const bool zv1 = (unsigned)(z0 + 1) < 112u;
  const float wz0 = 1.f - fz, wz1 = fz;
  float acc = 0.f;
#pragma unroll
  for (int dy = 0; dy < 2; ++dy) {
    const int yi = y0 + dy;
    const float wy = dy ? fy : 1.f - fy;
#pragma unroll
    for (int dx = 0; dx < 2; ++dx) {
      const int xi = x0 + dx;
      const float wx = dx ? fx : 1.f - fx;
      if ((unsigned)xi < 200u && (unsigned)yi < 56u) {
        const _Float16* bp = depth + ((size_t)n * 11200 + yi * 200 + xi) * 112;
        float v0 = zv0 ? (float)bp[z0] : 0.f;
        float v1 = zv1 ? (float)bp[z0 + 1] : 0.f;
        acc += (wx * wy) * (wz0 * v0 + wz1 * v1);
      }
    }
  }
  out[i] = acc;
}

// ---------------------------------------------------------------- launch
extern "C" void kernel_launch(void* const* d_in, const int* in_sizes, int n_in,
                              void* d_out, int out_size, void* d_ws, size_t ws_size,
                              hipStream_t stream) {
  (void)in_sizes; (void)n_in; (void)out_size; (void)ws_size;
  const float* img = (const float*)d_in[0];
  const float* sps = (const float*)d_in[1];
  const float* grids = (const float*)d_in[2];
  const float* rc_w = (const float*)d_in[3];
  const float* rc_b = (const float*)d_in[4];
  const float* rc_s = (const float*)d_in[5];
  const float* rc_t = (const float*)d_in[6];
  const float* fc1_w = (const float*)d_in[7];
  const float* fc1_b = (const float*)d_in[8];
  const float* fc2_w = (const float*)d_in[9];
  const float* fc2_b = (const float*)d_in[10];
  const float* se_rw = (const float*)d_in[11];
  const float* se_rb = (const float*)d_in[12];
  const float* se_ew = (const float*)d_in[13];
  const float* se_eb = (const float*)d_in[14];
  const float* bb_w1 = (const float*)d_in[15];
  const float* bb_s1 = (const float*)d_in[16];
  const float* bb_t1 = (const float*)d_in[17];
  const float* bb_w2 = (const float*)d_in[18];
  const float* bb_s2 = (const float*)d_in[19];
  const float* bb_t2 = (const float*)d_in[20];
  const float* dp_w = (const float*)d_in[21];
  const float* dp_b = (const float*)d_in[22];
  float* outp = (float*)d_out;

  char* ws = (char*)d_ws;
  _Float16* act16 = (_Float16*)(ws + 0);   // 22,937,600 B
  _Float16* depth16 = (_Float16*)(ws + 0); // reuses act16 slot (act16 dead post rc-conv)
  _Float16* xa = (_Float16*)(ws + 23068672);
  _Float16* xb = (_Float16*)(ws + 23068672 + 11534336);
  _Float16* yb = (_Float16*)(ws + 23068672 + 2 * 11534336);
  _Float16* wrc = (_Float16*)(ws + 57671680);              // 589,824 B
  _Float16* wdp = (_Float16*)(ws + 57671680 + 589824);     // 28,672 B
  _Float16* wbb = (_Float16*)(ws + 58327040);              // 1,769,472 B
  float* sig = (float*)(ws + 58327040 + 1769472);          // 2,048 B

  repack_all_kernel<<<dim3(4664), 256, 0, stream>>>(rc_w, bb_w1, bb_w2, dp_w, wrc, wbb, wdp);
  mlp_kernel<<<1, 128, 0, stream>>>(sps, fc1_w, fc1_b, fc2_w, fc2_b, se_rw, se_rb,
                                    se_ew, se_eb, sig);
  convert_kernel<<<dim3(4, 56, 4), 256, 0, stream>>>(img, act16);

  dim3 cgrid(13, 7, 4);  // 364 blocks, full 128-cout per block (round-2 tiling)
  conv3x3_kernel<256, 0><<<cgrid, 256, 0, stream>>>(act16, wrc, nullptr, rc_b, rc_s,
                                                    rc_t, sig, xa);
  _Float16* xcur = xa;
  _Float16* xnxt = xb;
  for (int i = 0; i < 3; ++i) {
    conv3x3_kernel<128, 1><<<cgrid, 256, 0, stream>>>(
        xcur, wbb + (size_t)(2 * i) * 147456, nullptr, nullptr, bb_s1 + i * 128,
        bb_t1 + i * 128, nullptr, yb);
    conv3x3_kernel<128, 2><<<cgrid, 256, 0, stream>>>(
        yb, wbb + (size_t)(2 * i + 1) * 147456, xcur, nullptr, bb_s2 + i * 128,
        bb_t2 + i * 128, nullptr, xnxt);
    _Float16* t = xcur;
    xcur = xnxt;
    xnxt = t;
  }

  depth_proj_softmax_kernel<<<dim3(700), 256, 0, stream>>>(xcur, wdp, dp_b, depth16);
  gridsample_kernel<<<dim3(4096), 256, 0, stream>>>(grids, depth16, outp);
}